// Round 5
// baseline (259.657 us; speedup 1.0000x reference)
//
#include <hip/hip_runtime.h>
#include <hip/hip_bf16.h>

#define NN 20000
#define NE 320000
#define FDIM 32
#define YS 544      // 16 conv basis blocks * 32 + 32 fc cols

typedef __attribute__((ext_vector_type(8))) short short8;
typedef __attribute__((ext_vector_type(4))) float f32x4;

__device__ __forceinline__ unsigned short f2bf(float v) {
    unsigned u = __float_as_uint(v);
    unsigned r = (u + 0x7fffu + ((u >> 16) & 1u)) >> 16;
    return (unsigned short)r;
}
__device__ __forceinline__ float bf2f(unsigned short s) {
    return __uint_as_float(((unsigned)s) << 16);
}
__device__ __forceinline__ unsigned short f2h(float v) {
    union { _Float16 h; unsigned short u; } cv;
    cv.h = (_Float16)v;
    return cv.u;
}
__device__ __forceinline__ float h2f(unsigned short u) {
    union { unsigned short u; _Float16 h; } cv;
    cv.u = u;
    return (float)cv.h;
}

struct WPtrs { const float* cw[4]; const float* fw[4]; };

// ---- fused: blocks [0,1250) histogram edges; rest build Wt (transposed [l][c][k])
__global__ __launch_bounds__(256) void histprep_kernel(const int* __restrict__ ei,
                                                       int* __restrict__ counts,
                                                       WPtrs wp,
                                                       unsigned short* __restrict__ wt) {
    int b = blockIdx.x;
    if (b < (NE + 255) / 256) {
        int e = b * 256 + threadIdx.x;
        if (e < NE) atomicAdd(&counts[ei[e]], 1);
    } else {
        int idx = (b - (NE + 255) / 256) * 256 + threadIdx.x;   // 4 * 544*32 = 69632
        if (idx >= 4 * YS * 32) return;
        int l = idx / (YS * 32);
        int r = idx - l * YS * 32;
        int c = r >> 5, k = r & 31;
        float v = (c < 512) ? wp.cw[l][((c >> 5) * 32 + k) * 32 + (c & 31)]
                            : wp.fw[l][k * 32 + (c & 31)];
        wt[idx] = f2bf(v);
    }
}

// ---- CSR build: single-block scan, 20 elements/thread, fully unrolled
__global__ __launch_bounds__(1024) void scan_kernel(const int* __restrict__ counts,
                                                    int* __restrict__ rowst,
                                                    int* __restrict__ cursor) {
    __shared__ int s[1024];
    int t = threadIdx.x;
    int base = t * 20;                    // 1024*20 = 20480 >= 20000
    int v[20];
    int sum = 0;
#pragma unroll
    for (int i = 0; i < 20; i++) {
        int idx = base + i;
        v[i] = (idx < NN) ? counts[idx] : 0;
        sum += v[i];
    }
    s[t] = sum;
    __syncthreads();
#pragma unroll
    for (int off = 1; off < 1024; off <<= 1) {
        int add = (t >= off) ? s[t - off] : 0;
        __syncthreads();
        s[t] += add;
        __syncthreads();
    }
    int run = s[t] - sum;                 // exclusive across threads
    if (t == 0) rowst[0] = 0;
#pragma unroll
    for (int i = 0; i < 20; i++) {
        int idx = base + i;
        if (idx < NN) {
            cursor[idx] = run;
            rowst[idx + 1] = run + v[i];
        }
        run += v[i];
    }
}

// ---- fused: blocks [0,1250) CSR-fill; blocks [1250,2500) gemm0 (feat @ Wt0 -> y)
__global__ __launch_bounds__(256) void fillgemm_kernel(const int* __restrict__ ei,
                                                       const int* __restrict__ ej,
                                                       const float* __restrict__ attr,
                                                       int* __restrict__ cursor,
                                                       uint4* __restrict__ emeta,
                                                       const float* __restrict__ feat,
                                                       const unsigned short* __restrict__ Wt,
                                                       unsigned short* __restrict__ y) {
    int b = blockIdx.x;
    if (b < (NE + 255) / 256) {
        int e = b * 256 + threadIdx.x;
        if (e >= NE) return;
        int i = ei[e], j = ej[e];
        int p = atomicAdd(&cursor[i], 1);
        float2 a = ((const float2*)attr)[e];
        float d0 = fminf(fmaxf(a.x, -1.f), 1.f);
        float d1 = fminf(fmaxf(a.y, -1.f), 1.f);
        float tx = (d0 + 1.f) * 1.5f;
        float ty = (d1 + 1.f) * 1.5f;
        int ix = min(2, max(0, (int)floorf(tx)));
        int iy = min(2, max(0, (int)floorf(ty)));
        float ux = tx - (float)ix;
        float uy = ty - (float)iy;
        float m = (i != j) ? 1.f : 0.f;   // centerIgnore
        unsigned w0 = (unsigned)f2h((1.f - ux) * (1.f - uy) * m)
                    | ((unsigned)f2h((1.f - ux) * uy * m) << 16);
        unsigned w1 = (unsigned)f2h(ux * (1.f - uy) * m)
                    | ((unsigned)f2h(ux * uy * m) << 16);
        uint4 mm;
        mm.x = (unsigned)j | ((unsigned)(ix * 4 + iy) << 16);
        mm.y = w0;
        mm.z = w1;
        mm.w = 0;
        emeta[p] = mm;
    } else {
        // MFMA gemm: y[n][544] = bf16(feat[n][0..31] @ W0)
        int wv = threadIdx.x >> 6, lane = threadIdx.x & 63;
        int m0 = (b - (NE + 255) / 256) * 16;   // 1250 blocks * 16 rows
        int row = lane & 15;
        int kb = (lane >> 4) * 8;
        const float* ar = feat + (size_t)(m0 + row) * 32 + kb;
        short8 av;
#pragma unroll
        for (int i = 0; i < 8; i++) av[i] = (short)f2bf(ar[i]);
        int orow0 = m0 + (lane >> 4) * 4;       // C/D: col=lane&15, row=(lane>>4)*4+r
        for (int ct = wv; ct < 34; ct += 4) {
            int col = ct * 16 + row;
            short8 bv = *(const short8*)(Wt + (size_t)col * 32 + kb);
            f32x4 acc = {0.f, 0.f, 0.f, 0.f};
            acc = __builtin_amdgcn_mfma_f32_16x16x32_bf16(av, bv, acc, 0, 0, 0);
#pragma unroll
            for (int r = 0; r < 4; r++)
                y[(size_t)(orow0 + r) * YS + col] = f2bf(acc[r]);
        }
    }
}

// ---- fused layer: node(l) gather for 4 nodes (1 node/wave) + mini-GEMM producing
// y(l+1) rows for those 4 nodes. mode: 0 = no residual (layer 0), 1 = residual.
__global__ __launch_bounds__(256) void fused_kernel(const unsigned short* __restrict__ yin,
                                                    const uint4* __restrict__ emeta,
                                                    const int* __restrict__ rowst,
                                                    const float* __restrict__ bias,
                                                    const float* __restrict__ ansin,
                                                    float* __restrict__ ansout,
                                                    const unsigned short* __restrict__ Wt,
                                                    unsigned short* __restrict__ yout,
                                                    int mode) {
    __shared__ float lds_a[4][32];
    int wv = threadIdx.x >> 6, lane = threadIdx.x & 63;
    int node = blockIdx.x * 4 + wv;
    int fp = lane & 15;
    int dy = (lane >> 4) & 1;
    int dx = lane >> 5;
    int r0 = rowst[node], r1 = rowst[node + 1];
    int sub = (dx * 4 + dy) * 32 + fp * 2;
    float a0 = 0.f, a1 = 0.f;

    if (r1 > r0) {
        int last = r1 - 1;
        uint4 mb[8];
#pragma unroll
        for (int k = 0; k < 8; k++) mb[k] = emeta[min(r0 + k, last)];
        for (int q = r0; q < r1; q += 8) {
            uint4 mc[8];
#pragma unroll
            for (int k = 0; k < 8; k++) mc[k] = mb[k];
            if (q + 8 < r1) {
#pragma unroll
                for (int k = 0; k < 8; k++) mb[k] = emeta[min(q + 8 + k, last)];
            }
            unsigned vv[8];
#pragma unroll
            for (int k = 0; k < 8; k++)
                vv[k] = *(const unsigned*)(yin + (size_t)(mc[k].x & 0xFFFF) * YS
                                               + (mc[k].x >> 16) * 32 + sub);
#pragma unroll
            for (int k = 0; k < 8; k++) {
                unsigned wb = dx ? mc[k].z : mc[k].y;
                float w = h2f((unsigned short)(dy ? (wb >> 16) : (wb & 0xFFFF)));
                w = (q + k < r1) ? w : 0.f;
                a0 += w * bf2f((unsigned short)(vv[k] & 0xFFFF));
                a1 += w * bf2f((unsigned short)(vv[k] >> 16));
            }
        }
    }

    a0 += __shfl_xor(a0, 32); a1 += __shfl_xor(a1, 32);
    a0 += __shfl_xor(a0, 16); a1 += __shfl_xor(a1, 16);
    if (lane < 16) {
        int f0 = fp * 2;
        unsigned fcb = *(const unsigned*)(yin + (size_t)node * YS + 512 + f0);
        float2 bs = ((const float2*)bias)[fp];
        float o0 = a0 + bf2f((unsigned short)(fcb & 0xFFFF)) + bs.x;
        float o1 = a1 + bf2f((unsigned short)(fcb >> 16)) + bs.y;
        if (mode) {
            float2 r = ((const float2*)ansin)[(size_t)node * 16 + fp];
            o0 += r.x; o1 += r.y;
        }
        float2 o; o.x = o0; o.y = o1;
        ((float2*)ansout)[(size_t)node * 16 + fp] = o;
        lds_a[wv][f0] = fmaxf(o0, 0.f);
        lds_a[wv][f0 + 1] = fmaxf(o1, 0.f);
    }
    __syncthreads();

    // mini-GEMM: yout[m0+n][c] = bf16( relu(ans)[m0+n][:] . Wt[c][:] )
    int m0 = blockIdx.x * 4;
    for (int c = threadIdx.x; c < YS; c += 256) {
        const short8* wp8 = (const short8*)(Wt + (size_t)c * 32);
        short8 w80 = wp8[0], w81 = wp8[1], w82 = wp8[2], w83 = wp8[3];
        float s0 = 0.f, s1 = 0.f, s2 = 0.f, s3 = 0.f;
#pragma unroll
        for (int k = 0; k < 32; k++) {
            short wk = (k < 8) ? w80[k] : (k < 16) ? w81[k - 8] : (k < 24) ? w82[k - 16] : w83[k - 24];
            float w = bf2f((unsigned short)wk);
            s0 += lds_a[0][k] * w;
            s1 += lds_a[1][k] * w;
            s2 += lds_a[2][k] * w;
            s3 += lds_a[3][k] * w;
        }
        yout[(size_t)(m0 + 0) * YS + c] = f2bf(s0);
        yout[(size_t)(m0 + 1) * YS + c] = f2bf(s1);
        yout[(size_t)(m0 + 2) * YS + c] = f2bf(s2);
        yout[(size_t)(m0 + 3) * YS + c] = f2bf(s3);
    }
}

// ---- final node kernel (layer 3): residual + scale -> d_out
__global__ __launch_bounds__(256) void node_kernel(const unsigned short* __restrict__ yin,
                                                   const uint4* __restrict__ emeta,
                                                   const int* __restrict__ rowst,
                                                   const float* __restrict__ bias,
                                                   const float* __restrict__ ansin,
                                                   float* __restrict__ ansout) {
    int node = blockIdx.x * 4 + (threadIdx.x >> 6);
    int lane = threadIdx.x & 63;
    int fp = lane & 15;
    int dy = (lane >> 4) & 1;
    int dx = lane >> 5;
    int r0 = rowst[node], r1 = rowst[node + 1];
    int sub = (dx * 4 + dy) * 32 + fp * 2;
    float a0 = 0.f, a1 = 0.f;

    if (r1 > r0) {
        int last = r1 - 1;
        uint4 mb[8];
#pragma unroll
        for (int k = 0; k < 8; k++) mb[k] = emeta[min(r0 + k, last)];
        for (int q = r0; q < r1; q += 8) {
            uint4 mc[8];
#pragma unroll
            for (int k = 0; k < 8; k++) mc[k] = mb[k];
            if (q + 8 < r1) {
#pragma unroll
                for (int k = 0; k < 8; k++) mb[k] = emeta[min(q + 8 + k, last)];
            }
            unsigned vv[8];
#pragma unroll
            for (int k = 0; k < 8; k++)
                vv[k] = *(const unsigned*)(yin + (size_t)(mc[k].x & 0xFFFF) * YS
                                               + (mc[k].x >> 16) * 32 + sub);
#pragma unroll
            for (int k = 0; k < 8; k++) {
                unsigned wb = dx ? mc[k].z : mc[k].y;
                float w = h2f((unsigned short)(dy ? (wb >> 16) : (wb & 0xFFFF)));
                w = (q + k < r1) ? w : 0.f;
                a0 += w * bf2f((unsigned short)(vv[k] & 0xFFFF));
                a1 += w * bf2f((unsigned short)(vv[k] >> 16));
            }
        }
    }

    a0 += __shfl_xor(a0, 32); a1 += __shfl_xor(a1, 32);
    a0 += __shfl_xor(a0, 16); a1 += __shfl_xor(a1, 16);
    if (lane < 16) {
        int f0 = fp * 2;
        unsigned fcb = *(const unsigned*)(yin + (size_t)node * YS + 512 + f0);
        float2 bs = ((const float2*)bias)[fp];
        float2 r = ((const float2*)ansin)[(size_t)node * 16 + fp];
        float o0 = (a0 + bf2f((unsigned short)(fcb & 0xFFFF)) + bs.x + r.x) * (1.f / 128.f);
        float o1 = (a1 + bf2f((unsigned short)(fcb >> 16)) + bs.y + r.y) * (1.f / 128.f);
        float2 o; o.x = o0; o.y = o1;
        ((float2*)ansout)[(size_t)node * 16 + fp] = o;
    }
}

extern "C" void kernel_launch(void* const* d_in, const int* in_sizes, int n_in,
                              void* d_out, int out_size, void* d_ws, size_t ws_size,
                              hipStream_t stream) {
    const float* feat = (const float*)d_in[0];
    const int* ei = (const int*)d_in[1];
    const int* ej = (const int*)d_in[2];
    const float* attr = (const float*)d_in[3];
    WPtrs wp;
    const float* fcB[4];
    if (n_in >= 16) {
        for (int l = 0; l < 4; l++) {
            wp.cw[l] = (const float*)d_in[4 + l];
            wp.fw[l] = (const float*)d_in[8 + l];
            fcB[l]   = (const float*)d_in[12 + l];
        }
    } else {
        const float* cb = (const float*)d_in[4];
        const float* fb = (const float*)d_in[5];
        const float* bb = (const float*)d_in[6];
        for (int l = 0; l < 4; l++) {
            wp.cw[l] = cb + (size_t)l * 16 * 32 * 32;
            wp.fw[l] = fb + (size_t)l * 32 * 32;
            fcB[l]   = bb + (size_t)l * 32;
        }
    }

    // workspace bump allocator (256B aligned)
    char* p = (char*)d_ws;
    auto alloc = [&](size_t bytes) -> void* {
        void* r = (void*)p;
        p += (bytes + 255) & ~(size_t)255;
        return r;
    };
    unsigned short* wt = (unsigned short*)alloc(4 * YS * 32 * sizeof(unsigned short));
    uint4* emeta  = (uint4*)alloc((size_t)NE * sizeof(uint4));
    int* counts   = (int*)alloc((size_t)NN * sizeof(int));
    int* cursor   = (int*)alloc((size_t)NN * sizeof(int));
    int* rowst    = (int*)alloc((size_t)(NN + 1) * sizeof(int));
    unsigned short* yA = (unsigned short*)alloc((size_t)NN * YS * sizeof(unsigned short));
    unsigned short* yB = (unsigned short*)alloc((size_t)NN * YS * sizeof(unsigned short));
    float* ans    = (float*)alloc((size_t)NN * FDIM * sizeof(float));
    float* outf   = (float*)d_out;

    hipMemsetAsync(counts, 0, (size_t)NN * sizeof(int), stream);

    int histBlocks = (NE + 255) / 256;
    int prepBlocks = (4 * YS * 32 + 255) / 256;
    histprep_kernel<<<histBlocks + prepBlocks, 256, 0, stream>>>(ei, counts, wp, wt);
    scan_kernel<<<1, 1024, 0, stream>>>(counts, rowst, cursor);
    fillgemm_kernel<<<histBlocks + NN / 16, 256, 0, stream>>>(ei, ej, attr, cursor, emeta,
                                                              feat, wt, yA);

    // fused layers: node(l) + gemm(l+1); y ping-pongs A->B->A->B
    fused_kernel<<<NN / 4, 256, 0, stream>>>(yA, emeta, rowst, fcB[0], ans, ans,
                                             wt + (size_t)1 * YS * 32, yB, 0);
    fused_kernel<<<NN / 4, 256, 0, stream>>>(yB, emeta, rowst, fcB[1], ans, ans,
                                             wt + (size_t)2 * YS * 32, yA, 1);
    fused_kernel<<<NN / 4, 256, 0, stream>>>(yA, emeta, rowst, fcB[2], ans, ans,
                                             wt + (size_t)3 * YS * 32, yB, 1);
    node_kernel<<<NN / 4, 256, 0, stream>>>(yB, emeta, rowst, fcB[3], ans, outf);
}